// Round 1
// baseline (242.899 us; speedup 1.0000x reference)
//
#include <hip/hip_runtime.h>
#include <stdint.h>

#define T_SEQ 2048
#define NB    2
#define DHD   128
#define NHQ   16
#define NHKV  4
#define SWIN  512
#define CDIM  2048
#define QKVN  3072

typedef __attribute__((ext_vector_type(8))) short short8;
typedef __attribute__((ext_vector_type(4))) float f32x4;
typedef __attribute__((address_space(3))) unsigned int lds_u32;
typedef __attribute__((address_space(1))) const unsigned int gbl_u32;

__device__ __forceinline__ unsigned short f2bf(float f) {
  unsigned int u = __float_as_uint(f);
  u += 0x7fffu + ((u >> 16) & 1u);
  return (unsigned short)(u >> 16);
}
__device__ __forceinline__ float bf2f(unsigned int h) {
  return __uint_as_float(h << 16);
}

// ---------------- fp32 -> bf16 (vectorized, grid-stride) ----------------
__global__ __launch_bounds__(256) void k_f2bf(const float* __restrict__ in,
                                              unsigned short* __restrict__ out, int n4) {
  int i = blockIdx.x * 256 + threadIdx.x;
  int stride = gridDim.x * 256;
  for (; i < n4; i += stride) {
    float4 v = reinterpret_cast<const float4*>(in)[i];
    uint2 o;
    o.x = ((unsigned int)f2bf(v.y) << 16) | f2bf(v.x);
    o.y = ((unsigned int)f2bf(v.w) << 16) | f2bf(v.z);
    reinterpret_cast<uint2*>(out)[i] = o;
  }
}

// ---------------- RoPE trig table: tbl[0..T*64) cos, [T*64..) sin ----------------
__global__ __launch_bounds__(256) void k_trig(float* __restrict__ tbl) {
  int i = blockIdx.x * 256 + threadIdx.x;
  if (i >= T_SEQ * 64) return;
  int t = i >> 6, f = i & 63;
  float invf = powf(10000.f, -(float)f * (1.f / 64.f));
  float ang = (float)t * invf;
  tbl[i] = cosf(ang);
  tbl[T_SEQ * 64 + i] = sinf(ang);
}

// ---------------- GEMM: C[M,N] = A[M,K] x B[N,K]^T, bf16 in / fp32 acc ----------------
// 128x128 tile, BK=32, 4 waves (2x2 of 64x64), global_load_lds width 16.
template<int OUT_BF16>
__global__ __launch_bounds__(256) void k_gemm_bt(const unsigned short* __restrict__ A,
                                                 const unsigned short* __restrict__ B,
                                                 void* __restrict__ Cout,
                                                 int M, int N, int K) {
  __shared__ __align__(16) unsigned short lA[128 * 32];
  __shared__ __align__(16) unsigned short lB[128 * 32];
  const int tid = threadIdx.x;
  const int lane = tid & 63, wid = tid >> 6;
  const int lr = lane & 15, lg = lane >> 4;
  const int wr = wid >> 1, wc = wid & 1;
  const int bx = blockIdx.x, by = blockIdx.y;

  f32x4 acc[4][4];
#pragma unroll
  for (int i = 0; i < 4; ++i)
#pragma unroll
    for (int j = 0; j < 4; ++j)
#pragma unroll
      for (int r = 0; r < 4; ++r) acc[i][j][r] = 0.f;

  const unsigned short* Abase = A + (size_t)by * 128 * K;
  const unsigned short* Bbase = B + (size_t)bx * 128 * K;

  for (int k0 = 0; k0 < K; k0 += 32) {
#pragma unroll
    for (int it = 0; it < 2; ++it) {
      int chunk = it * 256 + tid;        // 16B chunk id in tile
      int row = chunk >> 2;              // 4 chunks per 64B row
      int ce  = (chunk & 3) << 3;        // element offset in row
      int loff = it * 2048 + wid * 512;  // wave-uniform LDS element offset
      __builtin_amdgcn_global_load_lds((gbl_u32*)(Abase + (size_t)row * K + k0 + ce),
                                       (lds_u32*)(lA + loff), 16, 0, 0);
      __builtin_amdgcn_global_load_lds((gbl_u32*)(Bbase + (size_t)row * K + k0 + ce),
                                       (lds_u32*)(lB + loff), 16, 0, 0);
    }
    __syncthreads();
    short8 af[4], bfr[4];
#pragma unroll
    for (int mi = 0; mi < 4; ++mi)
      af[mi] = *reinterpret_cast<const short8*>(&lA[(wr * 64 + mi * 16 + lr) * 32 + lg * 8]);
#pragma unroll
    for (int ni = 0; ni < 4; ++ni)
      bfr[ni] = *reinterpret_cast<const short8*>(&lB[(wc * 64 + ni * 16 + lr) * 32 + lg * 8]);
#pragma unroll
    for (int mi = 0; mi < 4; ++mi)
#pragma unroll
      for (int ni = 0; ni < 4; ++ni)
        acc[mi][ni] = __builtin_amdgcn_mfma_f32_16x16x32_bf16(af[mi], bfr[ni], acc[mi][ni], 0, 0, 0);
    __syncthreads();
  }

#pragma unroll
  for (int mi = 0; mi < 4; ++mi) {
    const int row0 = by * 128 + wr * 64 + mi * 16 + lg * 4;
#pragma unroll
    for (int ni = 0; ni < 4; ++ni) {
      const int col = bx * 128 + wc * 64 + ni * 16 + lr;
#pragma unroll
      for (int r = 0; r < 4; ++r) {
        size_t idx = (size_t)(row0 + r) * N + col;
        if (OUT_BF16) ((unsigned short*)Cout)[idx] = f2bf(acc[mi][ni][r]);
        else          ((float*)Cout)[idx] = acc[mi][ni][r];
      }
    }
  }
}

// ---------------- RoPE + RMSNorm for Q and K heads ----------------
// job = row*20 + hh ; hh<16 -> Q head (folds 1/sqrt(DH)), else K head.
__global__ __launch_bounds__(256) void k_rope_rms(const unsigned short* __restrict__ qkv,
                                                  const float* __restrict__ tbl,
                                                  unsigned short* __restrict__ Qo,
                                                  unsigned short* __restrict__ Ko) {
  const int lane = threadIdx.x & 63, wid = threadIdx.x >> 6;
  const int job = blockIdx.x * 4 + wid;
  const int row = job / 20;
  const int hh  = job - row * 20;
  const int b = row >> 11, t = row & (T_SEQ - 1);
  const unsigned short* src;
  unsigned short* dst;
  float scale;
  if (hh < NHQ) {
    src = qkv + (size_t)row * QKVN + hh * DHD;
    dst = Qo + (((size_t)b * NHQ + hh) * T_SEQ + t) * DHD;
    scale = 0.0883883476483184f;  // 1/sqrt(128)
  } else {
    int h = hh - NHQ;
    src = qkv + (size_t)row * QKVN + CDIM + h * DHD;
    dst = Ko + (((size_t)b * NHKV + h) * T_SEQ + t) * DHD;
    scale = 1.f;
  }
  unsigned int pr = *reinterpret_cast<const unsigned int*>(src + lane * 2);
  float xe = bf2f(pr & 0xffffu), xo = bf2f(pr >> 16);
  float c = tbl[t * 64 + lane], s = tbl[T_SEQ * 64 + t * 64 + lane];
  float e = xe * c - xo * s;
  float o = xo * c + xe * s;
  float ss = e * e + o * o;
#pragma unroll
  for (int off = 1; off < 64; off <<= 1) ss += __shfl_xor(ss, off);
  float rn = rsqrtf(ss * (1.f / 128.f) + 1.1920929e-07f) * scale;
  unsigned short eb = f2bf(e * rn), ob = f2bf(o * rn);
  *reinterpret_cast<unsigned int*>(dst + lane * 2) = ((unsigned int)ob << 16) | eb;
}

// ---------------- V transpose: qkv[.,2560+h*128+d] -> Vt[b][h][d][t] ----------------
__global__ __launch_bounds__(256) void k_vtrans(const unsigned short* __restrict__ qkv,
                                                unsigned short* __restrict__ Vt) {
  __shared__ unsigned short tile[64][65];
  const int blk = blockIdx.x;
  const int dt = blk & 1;
  const int tt = (blk >> 1) & 31;
  const int h = (blk >> 6) & 3;
  const int b = blk >> 8;
  const int t0 = tt * 64, d0 = dt * 64;
#pragma unroll
  for (int i = 0; i < 16; ++i) {
    int idx = i * 256 + threadIdx.x;
    int tl = idx >> 6, dl = idx & 63;
    tile[tl][dl] = qkv[(size_t)(b * T_SEQ + t0 + tl) * QKVN + (CDIM + NHKV * DHD) + h * DHD + d0 + dl];
  }
  __syncthreads();
#pragma unroll
  for (int i = 0; i < 16; ++i) {
    int idx = i * 256 + threadIdx.x;
    int dl = idx >> 6, tl = idx & 63;
    Vt[((size_t)(b * NHKV + h) * DHD + d0 + dl) * T_SEQ + t0 + tl] = tile[tl][dl];
  }
}

// ---------------- windowed causal flash attention ----------------
// block = (b, h, 128-query tile); wave = 32 query rows; KV tiles of 32.
__global__ __launch_bounds__(256) void k_attn(const unsigned short* __restrict__ Q,
                                              const unsigned short* __restrict__ K,
                                              const unsigned short* __restrict__ Vt,
                                              unsigned short* __restrict__ Y) {
  __shared__ __align__(16) unsigned short pb[4][32 * 32];
  const int tid = threadIdx.x, lane = tid & 63, wid = tid >> 6;
  const int lr = lane & 15, lg = lane >> 4;
  const int blk = blockIdx.x;
  const int qt = blk & 15;
  const int h = (blk >> 4) & 15;
  const int b = blk >> 8;
  const int hkv = h >> 2;
  const int q0 = qt * 128 + wid * 32;

  const unsigned short* Qb = Q + (((size_t)b * NHQ + h) * T_SEQ + q0) * DHD;
  const unsigned short* Kb = K + ((size_t)b * NHKV + hkv) * T_SEQ * DHD;
  const unsigned short* Vb = Vt + ((size_t)b * NHKV + hkv) * DHD * T_SEQ;

  short8 aq[2][4];
#pragma unroll
  for (int mi = 0; mi < 2; ++mi)
#pragma unroll
    for (int kb = 0; kb < 4; ++kb)
      aq[mi][kb] = *reinterpret_cast<const short8*>(Qb + (size_t)(mi * 16 + lr) * DHD + kb * 32 + lg * 8);

  f32x4 accO[2][8];
  float m_[2][4], l_[2][4];
#pragma unroll
  for (int mi = 0; mi < 2; ++mi) {
#pragma unroll
    for (int nj = 0; nj < 8; ++nj)
#pragma unroll
      for (int r = 0; r < 4; ++r) accO[mi][nj][r] = 0.f;
#pragma unroll
    for (int r = 0; r < 4; ++r) { m_[mi][r] = -__builtin_inff(); l_[mi][r] = 0.f; }
  }

  int klo = q0 - (SWIN - 1); if (klo < 0) klo = 0;
  const int kt_lo = klo >> 5, kt_hi = (q0 + 31) >> 5;

  for (int kt = kt_lo; kt <= kt_hi; ++kt) {
    const int k0 = kt << 5;
    short8 bk[2][4];
#pragma unroll
    for (int ni = 0; ni < 2; ++ni)
#pragma unroll
      for (int kb = 0; kb < 4; ++kb)
        bk[ni][kb] = *reinterpret_cast<const short8*>(Kb + (size_t)(k0 + ni * 16 + lr) * DHD + kb * 32 + lg * 8);

    f32x4 s[2][2];
#pragma unroll
    for (int mi = 0; mi < 2; ++mi)
#pragma unroll
      for (int ni = 0; ni < 2; ++ni)
#pragma unroll
        for (int r = 0; r < 4; ++r) s[mi][ni][r] = 0.f;
#pragma unroll
    for (int kb = 0; kb < 4; ++kb)
#pragma unroll
      for (int mi = 0; mi < 2; ++mi)
#pragma unroll
        for (int ni = 0; ni < 2; ++ni)
          s[mi][ni] = __builtin_amdgcn_mfma_f32_16x16x32_bf16(aq[mi][kb], bk[ni][kb], s[mi][ni], 0, 0, 0);

#pragma unroll
    for (int mi = 0; mi < 2; ++mi) {
      const int qgb = q0 + mi * 16 + lg * 4;
      float tmax[4];
#pragma unroll
      for (int r = 0; r < 4; ++r) {
        const int qg = qgb + r;
#pragma unroll
        for (int ni = 0; ni < 2; ++ni) {
          const int kg = k0 + ni * 16 + lr;
          if (kg > qg || qg - kg >= SWIN) s[mi][ni][r] = -__builtin_inff();
        }
        tmax[r] = fmaxf(s[mi][0][r], s[mi][1][r]);
#pragma unroll
        for (int off = 1; off < 16; off <<= 1) tmax[r] = fmaxf(tmax[r], __shfl_xor(tmax[r], off));
      }
#pragma unroll
      for (int r = 0; r < 4; ++r) {
        float mn = fmaxf(m_[mi][r], tmax[r]);
        float da = m_[mi][r] - mn;
        float alpha = (da >= -60.f) ? __expf(da) : 0.f;
        m_[mi][r] = mn;
        float psum = 0.f;
#pragma unroll
        for (int ni = 0; ni < 2; ++ni) {
          float d = s[mi][ni][r] - mn;
          float p = (d >= -60.f) ? __expf(d) : 0.f;
          s[mi][ni][r] = p;
          psum += p;
        }
#pragma unroll
        for (int off = 1; off < 16; off <<= 1) psum += __shfl_xor(psum, off);
        l_[mi][r] = l_[mi][r] * alpha + psum;
#pragma unroll
        for (int nj = 0; nj < 8; ++nj) accO[mi][nj][r] *= alpha;
      }
#pragma unroll
      for (int r = 0; r < 4; ++r)
#pragma unroll
        for (int ni = 0; ni < 2; ++ni)
          pb[wid][(mi * 16 + lg * 4 + r) * 32 + ni * 16 + lr] = f2bf(s[mi][ni][r]);
    }

    short8 pf0 = *reinterpret_cast<const short8*>(&pb[wid][lr * 32 + lg * 8]);
    short8 pf1 = *reinterpret_cast<const short8*>(&pb[wid][(16 + lr) * 32 + lg * 8]);
#pragma unroll
    for (int nj = 0; nj < 8; ++nj) {
      short8 vf = *reinterpret_cast<const short8*>(Vb + (size_t)(nj * 16 + lr) * T_SEQ + k0 + lg * 8);
      accO[0][nj] = __builtin_amdgcn_mfma_f32_16x16x32_bf16(pf0, vf, accO[0][nj], 0, 0, 0);
      accO[1][nj] = __builtin_amdgcn_mfma_f32_16x16x32_bf16(pf1, vf, accO[1][nj], 0, 0, 0);
    }
  }

#pragma unroll
  for (int mi = 0; mi < 2; ++mi)
#pragma unroll
    for (int r = 0; r < 4; ++r) {
      float inv = 1.f / l_[mi][r];
      int qg = q0 + mi * 16 + lg * 4 + r;
      unsigned short* yrow = Y + ((size_t)b * T_SEQ + qg) * CDIM + h * DHD;
#pragma unroll
      for (int nj = 0; nj < 8; ++nj)
        yrow[nj * 16 + lr] = f2bf(accO[mi][nj][r] * inv);
    }
}

extern "C" void kernel_launch(void* const* d_in, const int* in_sizes, int n_in,
                              void* d_out, int out_size, void* d_ws, size_t ws_size,
                              hipStream_t stream) {
  const float* x     = (const float*)d_in[0];
  const float* wqkv  = (const float*)d_in[1];
  const float* wproj = (const float*)d_in[2];
  float* out = (float*)d_out;

  char* ws = (char*)d_ws;
  unsigned short* xb     = (unsigned short*)(ws + 0);         // 16 MB (reused as y)
  unsigned short* wqkvb  = (unsigned short*)(ws + 16777216);  // 12 MB
  unsigned short* wprojb = (unsigned short*)(ws + 29360128);  // 8 MB
  unsigned short* qkvb   = (unsigned short*)(ws + 37748736);  // 24 MB
  unsigned short* Qb     = (unsigned short*)(ws + 62914560);  // 16 MB
  unsigned short* Kb     = (unsigned short*)(ws + 79691776);  // 4 MB
  unsigned short* Vtb    = (unsigned short*)(ws + 83886080);  // 4 MB
  float* tbl             = (float*)(ws + 88080384);           // 1 MB
  unsigned short* yb     = xb;

  k_f2bf<<<2048, 256, 0, stream>>>(x, xb, (NB * T_SEQ * CDIM) / 4);
  k_f2bf<<<1536, 256, 0, stream>>>(wqkv, wqkvb, (QKVN * CDIM) / 4);
  k_f2bf<<<1024, 256, 0, stream>>>(wproj, wprojb, (CDIM * CDIM) / 4);
  k_trig<<<(T_SEQ * 64 + 255) / 256, 256, 0, stream>>>(tbl);

  k_gemm_bt<1><<<dim3(QKVN / 128, (NB * T_SEQ) / 128), 256, 0, stream>>>(
      xb, wqkvb, qkvb, NB * T_SEQ, QKVN, CDIM);
  k_rope_rms<<<(NB * T_SEQ * (NHQ + NHKV)) / 4, 256, 0, stream>>>(qkvb, tbl, Qb, Kb);
  k_vtrans<<<NB * NHKV * 32 * 2, 256, 0, stream>>>(qkvb, Vtb);
  k_attn<<<NB * NHQ * (T_SEQ / 128), 256, 0, stream>>>(Qb, Kb, Vtb, yb);
  k_gemm_bt<0><<<dim3(CDIM / 128, (NB * T_SEQ) / 128), 256, 0, stream>>>(
      yb, wprojb, out, NB * T_SEQ, CDIM, CDIM);
}

// Round 2
// 233.513 us; speedup vs baseline: 1.0402x; 1.0402x over previous
//
#include <hip/hip_runtime.h>
#include <stdint.h>

#define T_SEQ 2048
#define NB    2
#define DHD   128
#define NHQ   16
#define NHKV  4
#define SWIN  512
#define CDIM  2048
#define QKVN  3072

typedef __attribute__((ext_vector_type(8))) short short8;
typedef __attribute__((ext_vector_type(4))) float f32x4;
typedef __attribute__((ext_vector_type(16))) float f32x16;
typedef __attribute__((ext_vector_type(4))) unsigned int u32x4;
typedef __attribute__((address_space(3))) unsigned int lds_u32;
typedef __attribute__((address_space(1))) const unsigned int gbl_u32;

__device__ __forceinline__ unsigned short f2bf(float f) {
  unsigned int u = __float_as_uint(f);
  u += 0x7fffu + ((u >> 16) & 1u);
  return (unsigned short)(u >> 16);
}
__device__ __forceinline__ float bf2f(unsigned int h) {
  return __uint_as_float(h << 16);
}

// ---------------- fp32 -> bf16 (vectorized, grid-stride) ----------------
__global__ __launch_bounds__(256) void k_f2bf(const float* __restrict__ in,
                                              unsigned short* __restrict__ out, int n4) {
  int i = blockIdx.x * 256 + threadIdx.x;
  int stride = gridDim.x * 256;
  for (; i < n4; i += stride) {
    float4 v = reinterpret_cast<const float4*>(in)[i];
    uint2 o;
    o.x = ((unsigned int)f2bf(v.y) << 16) | f2bf(v.x);
    o.y = ((unsigned int)f2bf(v.w) << 16) | f2bf(v.z);
    reinterpret_cast<uint2*>(out)[i] = o;
  }
}

// ---------------- RoPE trig table: tbl[0..T*64) cos, [T*64..) sin ----------------
__global__ __launch_bounds__(256) void k_trig(float* __restrict__ tbl) {
  int i = blockIdx.x * 256 + threadIdx.x;
  if (i >= T_SEQ * 64) return;
  int t = i >> 6, f = i & 63;
  float invf = powf(10000.f, -(float)f * (1.f / 64.f));
  float ang = (float)t * invf;
  tbl[i] = cosf(ang);
  tbl[T_SEQ * 64 + i] = sinf(ang);
}

// ---------------- GEMM: C[M,N] = A[M,K] x B[N,K]^T, bf16 in / fp32 acc ----------------
template<int OUT_BF16>
__global__ __launch_bounds__(256) void k_gemm_bt(const unsigned short* __restrict__ A,
                                                 const unsigned short* __restrict__ B,
                                                 void* __restrict__ Cout,
                                                 int M, int N, int K) {
  __shared__ __align__(16) unsigned short lA[128 * 32];
  __shared__ __align__(16) unsigned short lB[128 * 32];
  const int tid = threadIdx.x;
  const int lane = tid & 63, wid = tid >> 6;
  const int lr = lane & 15, lg = lane >> 4;
  const int wr = wid >> 1, wc = wid & 1;
  const int bx = blockIdx.x, by = blockIdx.y;

  f32x4 acc[4][4];
#pragma unroll
  for (int i = 0; i < 4; ++i)
#pragma unroll
    for (int j = 0; j < 4; ++j)
#pragma unroll
      for (int r = 0; r < 4; ++r) acc[i][j][r] = 0.f;

  const unsigned short* Abase = A + (size_t)by * 128 * K;
  const unsigned short* Bbase = B + (size_t)bx * 128 * K;

  for (int k0 = 0; k0 < K; k0 += 32) {
#pragma unroll
    for (int it = 0; it < 2; ++it) {
      int chunk = it * 256 + tid;
      int row = chunk >> 2;
      int ce  = (chunk & 3) << 3;
      int loff = it * 2048 + wid * 512;
      __builtin_amdgcn_global_load_lds((gbl_u32*)(Abase + (size_t)row * K + k0 + ce),
                                       (lds_u32*)(lA + loff), 16, 0, 0);
      __builtin_amdgcn_global_load_lds((gbl_u32*)(Bbase + (size_t)row * K + k0 + ce),
                                       (lds_u32*)(lB + loff), 16, 0, 0);
    }
    __syncthreads();
    short8 af[4], bfr[4];
#pragma unroll
    for (int mi = 0; mi < 4; ++mi)
      af[mi] = *reinterpret_cast<const short8*>(&lA[(wr * 64 + mi * 16 + lr) * 32 + lg * 8]);
#pragma unroll
    for (int ni = 0; ni < 4; ++ni)
      bfr[ni] = *reinterpret_cast<const short8*>(&lB[(wc * 64 + ni * 16 + lr) * 32 + lg * 8]);
#pragma unroll
    for (int mi = 0; mi < 4; ++mi)
#pragma unroll
      for (int ni = 0; ni < 4; ++ni)
        acc[mi][ni] = __builtin_amdgcn_mfma_f32_16x16x32_bf16(af[mi], bfr[ni], acc[mi][ni], 0, 0, 0);
    __syncthreads();
  }

#pragma unroll
  for (int mi = 0; mi < 4; ++mi) {
    const int row0 = by * 128 + wr * 64 + mi * 16 + lg * 4;
#pragma unroll
    for (int ni = 0; ni < 4; ++ni) {
      const int col = bx * 128 + wc * 64 + ni * 16 + lr;
#pragma unroll
      for (int r = 0; r < 4; ++r) {
        size_t idx = (size_t)(row0 + r) * N + col;
        if (OUT_BF16) ((unsigned short*)Cout)[idx] = f2bf(acc[mi][ni][r]);
        else          ((float*)Cout)[idx] = acc[mi][ni][r];
      }
    }
  }
}

// ---------------- RoPE + RMSNorm for Q and K heads ----------------
__global__ __launch_bounds__(256) void k_rope_rms(const unsigned short* __restrict__ qkv,
                                                  const float* __restrict__ tbl,
                                                  unsigned short* __restrict__ Qo,
                                                  unsigned short* __restrict__ Ko) {
  const int lane = threadIdx.x & 63, wid = threadIdx.x >> 6;
  const int job = blockIdx.x * 4 + wid;
  const int row = job / 20;
  const int hh  = job - row * 20;
  const int b = row >> 11, t = row & (T_SEQ - 1);
  const unsigned short* src;
  unsigned short* dst;
  float scale;
  if (hh < NHQ) {
    src = qkv + (size_t)row * QKVN + hh * DHD;
    dst = Qo + (((size_t)b * NHQ + hh) * T_SEQ + t) * DHD;
    scale = 0.0883883476483184f;  // 1/sqrt(128)
  } else {
    int h = hh - NHQ;
    src = qkv + (size_t)row * QKVN + CDIM + h * DHD;
    dst = Ko + (((size_t)b * NHKV + h) * T_SEQ + t) * DHD;
    scale = 1.f;
  }
  unsigned int pr = *reinterpret_cast<const unsigned int*>(src + lane * 2);
  float xe = bf2f(pr & 0xffffu), xo = bf2f(pr >> 16);
  float c = tbl[t * 64 + lane], s = tbl[T_SEQ * 64 + t * 64 + lane];
  float e = xe * c - xo * s;
  float o = xo * c + xe * s;
  float ss = e * e + o * o;
#pragma unroll
  for (int off = 1; off < 64; off <<= 1) ss += __shfl_xor(ss, off);
  float rn = rsqrtf(ss * (1.f / 128.f) + 1.1920929e-07f) * scale;
  unsigned short eb = f2bf(e * rn), ob = f2bf(o * rn);
  *reinterpret_cast<unsigned int*>(dst + lane * 2) = ((unsigned int)ob << 16) | eb;
}

// ---------------- V transpose: qkv[.,2560+h*128+d] -> Vt[b][h][d][t] ----------------
__global__ __launch_bounds__(256) void k_vtrans(const unsigned short* __restrict__ qkv,
                                                unsigned short* __restrict__ Vt) {
  __shared__ unsigned short tile[64][65];
  const int blk = blockIdx.x;
  const int dt = blk & 1;
  const int tt = (blk >> 1) & 31;
  const int h = (blk >> 6) & 3;
  const int b = blk >> 8;
  const int t0 = tt * 64, d0 = dt * 64;
#pragma unroll
  for (int i = 0; i < 16; ++i) {
    int idx = i * 256 + threadIdx.x;
    int tl = idx >> 6, dl = idx & 63;
    tile[tl][dl] = qkv[(size_t)(b * T_SEQ + t0 + tl) * QKVN + (CDIM + NHKV * DHD) + h * DHD + d0 + dl];
  }
  __syncthreads();
#pragma unroll
  for (int i = 0; i < 16; ++i) {
    int idx = i * 256 + threadIdx.x;
    int dl = idx >> 6, tl = idx & 63;
    Vt[((size_t)(b * NHKV + h) * DHD + d0 + dl) * T_SEQ + t0 + tl] = tile[tl][dl];
  }
}

// ---------------- windowed causal flash attention, swapped 32x32 MFMA ----------------
// block = (b, h, 128-query tile); wave = 32 query rows; KV tiles of 32 keys.
// QK^T: s = mfma_32x32x16(K, Q) -> lane holds q = lane&31, 16 k-values.
// P packed via v_cvt_pk_bf16_f32 + v_permlane32_swap (T12); PV: mfma(Vt, P).
__global__ __launch_bounds__(256) void k_attn(const unsigned short* __restrict__ Q,
                                              const unsigned short* __restrict__ K,
                                              const unsigned short* __restrict__ Vt,
                                              unsigned short* __restrict__ Y) {
  __shared__ __align__(16) unsigned short ob[4][32 * 136];
  const int tid = threadIdx.x, lane = tid & 63, wid = tid >> 6;
  const int l31 = lane & 31, hi = lane >> 5;
  const int blk = blockIdx.x;
  const int qt = blk & 15;
  const int h = (blk >> 4) & 15;
  const int b = blk >> 8;
  const int hkv = h >> 2;
  const int q0 = qt * 128 + wid * 32;

  const unsigned short* Qb = Q + (((size_t)b * NHQ + h) * T_SEQ + q0) * DHD;
  const unsigned short* Kb = K + ((size_t)b * NHKV + hkv) * T_SEQ * DHD;
  const unsigned short* Vb = Vt + ((size_t)b * NHKV + hkv) * DHD * T_SEQ;

  // Q fragments (B-operand: lane holds row q=l31, d-elems hi*8..+8 per 16-slice)
  short8 qf[8];
#pragma unroll
  for (int ds = 0; ds < 8; ++ds)
    qf[ds] = *reinterpret_cast<const short8*>(Qb + (size_t)l31 * DHD + ds * 16 + hi * 8);

  f32x16 accO[4];
#pragma unroll
  for (int dt = 0; dt < 4; ++dt)
#pragma unroll
    for (int r = 0; r < 16; ++r) accO[dt][r] = 0.f;
  float m = -1e30f, l = 0.f;

  int klo = q0 - (SWIN - 1); if (klo < 0) klo = 0;
  const int kt_lo = klo >> 5, kt_hi = q0 >> 5;
  const int qg = q0 + l31;

  for (int kt = kt_lo; kt <= kt_hi; ++kt) {
    const int k0 = kt << 5;
    // K fragments (A-operand: lane holds row k=k0+l31, d-elems hi*8..+8)
    short8 kf[8];
#pragma unroll
    for (int ds = 0; ds < 8; ++ds)
      kf[ds] = *reinterpret_cast<const short8*>(Kb + (size_t)(k0 + l31) * DHD + ds * 16 + hi * 8);

    f32x16 s;
#pragma unroll
    for (int r = 0; r < 16; ++r) s[r] = 0.f;
#pragma unroll
    for (int ds = 0; ds < 8; ++ds)
      s = __builtin_amdgcn_mfma_f32_32x32x16_bf16(kf[ds], qf[ds], s, 0, 0, 0);

    // mask only boundary tiles (wave-uniform branch)
    if (k0 < q0 - 480 || k0 >= q0) {
#pragma unroll
      for (int r = 0; r < 16; ++r) {
        int kk = k0 + (r & 3) + 8 * (r >> 2) + 4 * hi;
        if (kk > qg || qg - kk >= SWIN) s[r] = -1e30f;
      }
    }

    // row max: 15 local + one cross-half exchange
    float tmax = s[0];
#pragma unroll
    for (int r = 1; r < 16; ++r) tmax = fmaxf(tmax, s[r]);
    tmax = fmaxf(tmax, __shfl_xor(tmax, 32));

    float mn = m;
    if (!__all(tmax <= m + 8.f)) {          // T13 defer-rescale
      mn = fmaxf(m, tmax);
      float alpha = __expf(m - mn);
      l *= alpha;
#pragma unroll
      for (int dt = 0; dt < 4; ++dt)
#pragma unroll
        for (int r = 0; r < 16; ++r) accO[dt][r] *= alpha;
      m = mn;
    }

    float ps = 0.f;
#pragma unroll
    for (int r = 0; r < 16; ++r) { s[r] = __expf(s[r] - mn); ps += s[r]; }
    ps += __shfl_xor(ps, 32);
    l += ps;

    // pack P to bf16 fragments: regs r -> k = (r&3)+8*(r>>2)+4*hi
    unsigned int w[8];
#pragma unroll
    for (int j = 0; j < 8; ++j)
      asm("v_cvt_pk_bf16_f32 %0, %1, %2" : "=v"(w[j]) : "v"(s[2 * j]), "v"(s[2 * j + 1]));
    asm("v_permlane32_swap_b32 %0, %1" : "+v"(w[0]), "+v"(w[2]));
    asm("v_permlane32_swap_b32 %0, %1" : "+v"(w[1]), "+v"(w[3]));
    asm("v_permlane32_swap_b32 %0, %1" : "+v"(w[4]), "+v"(w[6]));
    asm("v_permlane32_swap_b32 %0, %1" : "+v"(w[5]), "+v"(w[7]));
    u32x4 a0 = {w[0], w[1], w[2], w[3]};
    u32x4 a1 = {w[4], w[5], w[6], w[7]};
    short8 pf0 = __builtin_bit_cast(short8, a0);
    short8 pf1 = __builtin_bit_cast(short8, a1);

    // PV: accO[dt] += Vt-rows(d) x P-rows(q); C col = q stays lane-local
#pragma unroll
    for (int dt = 0; dt < 4; ++dt) {
      const unsigned short* vrow = Vb + (size_t)(dt * 32 + l31) * T_SEQ + k0 + hi * 8;
      short8 vf0 = *reinterpret_cast<const short8*>(vrow);
      short8 vf1 = *reinterpret_cast<const short8*>(vrow + 16);
      accO[dt] = __builtin_amdgcn_mfma_f32_32x32x16_bf16(vf0, pf0, accO[dt], 0, 0, 0);
      accO[dt] = __builtin_amdgcn_mfma_f32_32x32x16_bf16(vf1, pf1, accO[dt], 0, 0, 0);
    }
  }

  // epilogue: O[q][d] -> LDS (pad 136) -> coalesced global store
  float inv = 1.f / l;
  unsigned short* obw = &ob[wid][0];
#pragma unroll
  for (int dt = 0; dt < 4; ++dt)
#pragma unroll
    for (int j = 0; j < 8; ++j) {
      float a = accO[dt][2 * j] * inv, c = accO[dt][2 * j + 1] * inv;
      unsigned int wv;
      asm("v_cvt_pk_bf16_f32 %0, %1, %2" : "=v"(wv) : "v"(a), "v"(c));
      int d = dt * 32 + 2 * (j & 1) + 8 * (j >> 1) + 4 * hi;
      *reinterpret_cast<unsigned int*>(obw + (size_t)l31 * 136 + d) = wv;
    }
  __syncthreads();
#pragma unroll
  for (int i = 0; i < 8; ++i) {
    int chunk = i * 64 + lane;
    int row = chunk >> 4, c8 = chunk & 15;
    short8 v = *reinterpret_cast<const short8*>(obw + row * 136 + c8 * 8);
    *reinterpret_cast<short8*>(Y + ((size_t)(b * T_SEQ) + q0 + row) * CDIM + h * DHD + c8 * 8) = v;
  }
}

extern "C" void kernel_launch(void* const* d_in, const int* in_sizes, int n_in,
                              void* d_out, int out_size, void* d_ws, size_t ws_size,
                              hipStream_t stream) {
  const float* x     = (const float*)d_in[0];
  const float* wqkv  = (const float*)d_in[1];
  const float* wproj = (const float*)d_in[2];
  float* out = (float*)d_out;

  char* ws = (char*)d_ws;
  unsigned short* xb     = (unsigned short*)(ws + 0);         // 16 MB (reused as y)
  unsigned short* wqkvb  = (unsigned short*)(ws + 16777216);  // 12 MB
  unsigned short* wprojb = (unsigned short*)(ws + 29360128);  // 8 MB
  unsigned short* qkvb   = (unsigned short*)(ws + 37748736);  // 24 MB
  unsigned short* Qb     = (unsigned short*)(ws + 62914560);  // 16 MB
  unsigned short* Kb     = (unsigned short*)(ws + 79691776);  // 4 MB
  unsigned short* Vtb    = (unsigned short*)(ws + 83886080);  // 4 MB
  float* tbl             = (float*)(ws + 88080384);           // 1 MB
  unsigned short* yb     = xb;

  k_f2bf<<<2048, 256, 0, stream>>>(x, xb, (NB * T_SEQ * CDIM) / 4);
  k_f2bf<<<1536, 256, 0, stream>>>(wqkv, wqkvb, (QKVN * CDIM) / 4);
  k_f2bf<<<1024, 256, 0, stream>>>(wproj, wprojb, (CDIM * CDIM) / 4);
  k_trig<<<(T_SEQ * 64 + 255) / 256, 256, 0, stream>>>(tbl);

  k_gemm_bt<1><<<dim3(QKVN / 128, (NB * T_SEQ) / 128), 256, 0, stream>>>(
      xb, wqkvb, qkvb, NB * T_SEQ, QKVN, CDIM);
  k_rope_rms<<<(NB * T_SEQ * (NHQ + NHKV)) / 4, 256, 0, stream>>>(qkvb, tbl, Qb, Kb);
  k_vtrans<<<NB * NHKV * 32 * 2, 256, 0, stream>>>(qkvb, Vtb);
  k_attn<<<NB * NHQ * (T_SEQ / 128), 256, 0, stream>>>(Qb, Kb, Vtb, yb);
  k_gemm_bt<0><<<dim3(CDIM / 128, (NB * T_SEQ) / 128), 256, 0, stream>>>(
      yb, wprojb, out, NB * T_SEQ, CDIM, CDIM);
}

// Round 3
// 215.561 us; speedup vs baseline: 1.1268x; 1.0833x over previous
//
#include <hip/hip_runtime.h>
#include <stdint.h>

#define T_SEQ 2048
#define NB    2
#define DHD   128
#define NHQ   16
#define NHKV  4
#define SWIN  512
#define CDIM  2048
#define QKVN  3072
#define GBK   32

typedef __attribute__((ext_vector_type(8))) short short8;
typedef __attribute__((ext_vector_type(4))) float f32x4;
typedef __attribute__((ext_vector_type(16))) float f32x16;
typedef __attribute__((ext_vector_type(4))) unsigned int u32x4;
typedef __attribute__((address_space(3))) unsigned int lds_u32;
typedef __attribute__((address_space(1))) const unsigned int gbl_u32;

__device__ __forceinline__ unsigned short f2bf(float f) {
  unsigned int u = __float_as_uint(f);
  u += 0x7fffu + ((u >> 16) & 1u);
  return (unsigned short)(u >> 16);
}
__device__ __forceinline__ float bf2f(unsigned int h) {
  return __uint_as_float(h << 16);
}

// ---------------- fp32 -> bf16 (vectorized, grid-stride) ----------------
__global__ __launch_bounds__(256) void k_f2bf(const float* __restrict__ in,
                                              unsigned short* __restrict__ out, int n4) {
  int i = blockIdx.x * 256 + threadIdx.x;
  int stride = gridDim.x * 256;
  for (; i < n4; i += stride) {
    float4 v = reinterpret_cast<const float4*>(in)[i];
    uint2 o;
    o.x = ((unsigned int)f2bf(v.y) << 16) | f2bf(v.x);
    o.y = ((unsigned int)f2bf(v.w) << 16) | f2bf(v.z);
    reinterpret_cast<uint2*>(out)[i] = o;
  }
}

// ---------------- RoPE trig table ----------------
__global__ __launch_bounds__(256) void k_trig(float* __restrict__ tbl) {
  int i = blockIdx.x * 256 + threadIdx.x;
  if (i >= T_SEQ * 64) return;
  int t = i >> 6, f = i & 63;
  float invf = powf(10000.f, -(float)f * (1.f / 64.f));
  float ang = (float)t * invf;
  tbl[i] = cosf(ang);
  tbl[T_SEQ * 64 + i] = sinf(ang);
}

// ---------------- 256x256 deep-pipelined GEMM: C = A[M,K] x B[N,K]^T ----------------
// 8 waves (2Mx4N), BK=32, ring of 4 LDS K-tile buffers (128 KiB), counted vmcnt(8),
// raw s_barrier (1 per K-step), T2 read-swizzle (byte ^= ((row>>1)&3)<<4, inverse on
// global source so global_load_lds dest stays linear), T5 setprio around MFMA cluster.
template<int OUT_BF16>
__global__ __launch_bounds__(512, 2) void k_gemm256(const unsigned short* __restrict__ A,
                                                    const unsigned short* __restrict__ B,
                                                    void* __restrict__ Cout,
                                                    int M, int N, int K, int nbx) {
  extern __shared__ __align__(16) char lds[];  // 4 slots x (A 16KB + B 16KB) = 128 KiB
  const int tid = threadIdx.x, lane = tid & 63, wid = tid >> 6;
  const int lr = lane & 15, lg = lane >> 4;
  const int wr = wid >> 2, wcn = wid & 3;

  // T1: bijective XCD swizzle (gridDim.x % 8 == 0)
  const int nwg = gridDim.x, cpx = nwg >> 3;
  const int id = (int)blockIdx.x;
  const int sid = (id & 7) * cpx + (id >> 3);
  const int by = sid / nbx, bx = sid - by * nbx;

  const unsigned short* Ab = A + (size_t)by * 256 * K;
  const unsigned short* Bb = B + (size_t)bx * 256 * K;

  // staging geometry: pass p covers rows p*128..+128; chunk=(p*512+tid), row=chunk>>2,
  // 16B block blk=chunk&3; source col pre-swizzled: colbyte = blk*16 ^ ((row>>1)&3)<<4
  const int row0 = tid >> 2;
  const int row1 = row0 + 128;
  const int blk  = tid & 3;
  const int col0 = ((blk * 16) ^ (((row0 >> 1) & 3) << 4)) >> 1;
  const int col1 = ((blk * 16) ^ (((row1 >> 1) & 3) << 4)) >> 1;
  const unsigned short* pA0 = Ab + (size_t)row0 * K + col0;
  const unsigned short* pA1 = Ab + (size_t)row1 * K + col1;
  const unsigned short* pB0 = Bb + (size_t)row0 * K + col0;
  const unsigned short* pB1 = Bb + (size_t)row1 * K + col1;

  // read-side swizzled fragment offsets
  const int sw  = ((lg ^ ((lr >> 1) & 3)) << 4);
  const int arb = (wr * 128 + lr) * 64 + sw;      // + mi*1024
  const int brb = (wcn * 64 + lr) * 64 + sw;      // + ni*1024

  f32x4 acc[8][4];
#pragma unroll
  for (int mi = 0; mi < 8; ++mi)
#pragma unroll
    for (int ni = 0; ni < 4; ++ni)
#pragma unroll
      for (int r = 0; r < 4; ++r) acc[mi][ni][r] = 0.f;

#define STAGE(t) do {                                                                  \
    const int sl_ = (t) & 3; const int ko_ = (t) * GBK;                                \
    __builtin_amdgcn_global_load_lds((gbl_u32*)(pA0 + ko_),                            \
        (lds_u32*)(lds + sl_ * 16384 + wid * 1024), 16, 0, 0);                         \
    __builtin_amdgcn_global_load_lds((gbl_u32*)(pA1 + ko_),                            \
        (lds_u32*)(lds + sl_ * 16384 + 8192 + wid * 1024), 16, 0, 0);                  \
    __builtin_amdgcn_global_load_lds((gbl_u32*)(pB0 + ko_),                            \
        (lds_u32*)(lds + 65536 + sl_ * 16384 + wid * 1024), 16, 0, 0);                 \
    __builtin_amdgcn_global_load_lds((gbl_u32*)(pB1 + ko_),                            \
        (lds_u32*)(lds + 65536 + sl_ * 16384 + 8192 + wid * 1024), 16, 0, 0);          \
  } while (0)

#define COMPUTE(t) do {                                                                \
    const int sl_ = (t) & 3;                                                           \
    const char* As_ = lds + sl_ * 16384;                                               \
    const char* Bs_ = lds + 65536 + sl_ * 16384;                                       \
    short8 afr[8], bfr[4];                                                             \
    _Pragma("unroll") for (int mi = 0; mi < 8; ++mi)                                   \
      afr[mi] = *reinterpret_cast<const short8*>(As_ + arb + mi * 1024);               \
    _Pragma("unroll") for (int ni = 0; ni < 4; ++ni)                                   \
      bfr[ni] = *reinterpret_cast<const short8*>(Bs_ + brb + ni * 1024);               \
    __builtin_amdgcn_s_setprio(1);                                                     \
    _Pragma("unroll") for (int mi = 0; mi < 8; ++mi)                                   \
      _Pragma("unroll") for (int ni = 0; ni < 4; ++ni)                                 \
        acc[mi][ni] = __builtin_amdgcn_mfma_f32_16x16x32_bf16(afr[mi], bfr[ni],        \
                                                              acc[mi][ni], 0, 0, 0);   \
    __builtin_amdgcn_s_setprio(0);                                                     \
  } while (0)

#define WAITBAR(n) do {                                                                \
    asm volatile("s_waitcnt vmcnt(" #n ")" ::: "memory");                              \
    __builtin_amdgcn_s_barrier();                                                      \
    asm volatile("" ::: "memory");                                                     \
  } while (0)

  const int nt = K / GBK;
  STAGE(0); STAGE(1); STAGE(2);
  for (int t = 0; t < nt - 3; ++t) {
    WAITBAR(8);
    STAGE(t + 3);
    COMPUTE(t);
  }
  WAITBAR(8); COMPUTE(nt - 3);
  WAITBAR(4); COMPUTE(nt - 2);
  WAITBAR(0); COMPUTE(nt - 1);

#undef STAGE
#undef COMPUTE
#undef WAITBAR

#pragma unroll
  for (int mi = 0; mi < 8; ++mi) {
    const int row0c = by * 256 + wr * 128 + mi * 16 + lg * 4;
#pragma unroll
    for (int ni = 0; ni < 4; ++ni) {
      const int col = bx * 256 + wcn * 64 + ni * 16 + lr;
#pragma unroll
      for (int r = 0; r < 4; ++r) {
        size_t idx = (size_t)(row0c + r) * N + col;
        if (OUT_BF16) ((unsigned short*)Cout)[idx] = f2bf(acc[mi][ni][r]);
        else          ((float*)Cout)[idx] = acc[mi][ni][r];
      }
    }
  }
}

// ---------------- RoPE + RMSNorm for Q and K heads ----------------
__global__ __launch_bounds__(256) void k_rope_rms(const unsigned short* __restrict__ qkv,
                                                  const float* __restrict__ tbl,
                                                  unsigned short* __restrict__ Qo,
                                                  unsigned short* __restrict__ Ko) {
  const int lane = threadIdx.x & 63, wid = threadIdx.x >> 6;
  const int job = blockIdx.x * 4 + wid;
  const int row = job / 20;
  const int hh  = job - row * 20;
  const int b = row >> 11, t = row & (T_SEQ - 1);
  const unsigned short* src;
  unsigned short* dst;
  float scale;
  if (hh < NHQ) {
    src = qkv + (size_t)row * QKVN + hh * DHD;
    dst = Qo + (((size_t)b * NHQ + hh) * T_SEQ + t) * DHD;
    scale = 0.0883883476483184f;  // 1/sqrt(128)
  } else {
    int h = hh - NHQ;
    src = qkv + (size_t)row * QKVN + CDIM + h * DHD;
    dst = Ko + (((size_t)b * NHKV + h) * T_SEQ + t) * DHD;
    scale = 1.f;
  }
  unsigned int pr = *reinterpret_cast<const unsigned int*>(src + lane * 2);
  float xe = bf2f(pr & 0xffffu), xo = bf2f(pr >> 16);
  float c = tbl[t * 64 + lane], s = tbl[T_SEQ * 64 + t * 64 + lane];
  float e = xe * c - xo * s;
  float o = xo * c + xe * s;
  float ss = e * e + o * o;
#pragma unroll
  for (int off = 1; off < 64; off <<= 1) ss += __shfl_xor(ss, off);
  float rn = rsqrtf(ss * (1.f / 128.f) + 1.1920929e-07f) * scale;
  unsigned short eb = f2bf(e * rn), ob = f2bf(o * rn);
  *reinterpret_cast<unsigned int*>(dst + lane * 2) = ((unsigned int)ob << 16) | eb;
}

// ---------------- V transpose ----------------
__global__ __launch_bounds__(256) void k_vtrans(const unsigned short* __restrict__ qkv,
                                                unsigned short* __restrict__ Vt) {
  __shared__ unsigned short tile[64][65];
  const int blk = blockIdx.x;
  const int dt = blk & 1;
  const int tt = (blk >> 1) & 31;
  const int h = (blk >> 6) & 3;
  const int b = blk >> 8;
  const int t0 = tt * 64, d0 = dt * 64;
#pragma unroll
  for (int i = 0; i < 16; ++i) {
    int idx = i * 256 + threadIdx.x;
    int tl = idx >> 6, dl = idx & 63;
    tile[tl][dl] = qkv[(size_t)(b * T_SEQ + t0 + tl) * QKVN + (CDIM + NHKV * DHD) + h * DHD + d0 + dl];
  }
  __syncthreads();
#pragma unroll
  for (int i = 0; i < 16; ++i) {
    int idx = i * 256 + threadIdx.x;
    int dl = idx >> 6, tl = idx & 63;
    Vt[((size_t)(b * NHKV + h) * DHD + d0 + dl) * T_SEQ + t0 + tl] = tile[tl][dl];
  }
}

// ---------------- windowed causal flash attention, swapped 32x32 MFMA ----------------
__global__ __launch_bounds__(256) void k_attn(const unsigned short* __restrict__ Q,
                                              const unsigned short* __restrict__ K,
                                              const unsigned short* __restrict__ Vt,
                                              unsigned short* __restrict__ Y) {
  __shared__ __align__(16) unsigned short ob[4][32 * 136];
  const int tid = threadIdx.x, lane = tid & 63, wid = tid >> 6;
  const int l31 = lane & 31, hi = lane >> 5;
  const int blk = blockIdx.x;
  const int qt = blk & 15;
  const int h = (blk >> 4) & 15;
  const int b = blk >> 8;
  const int hkv = h >> 2;
  const int q0 = qt * 128 + wid * 32;

  const unsigned short* Qb = Q + (((size_t)b * NHQ + h) * T_SEQ + q0) * DHD;
  const unsigned short* Kb = K + ((size_t)b * NHKV + hkv) * T_SEQ * DHD;
  const unsigned short* Vb = Vt + ((size_t)b * NHKV + hkv) * DHD * T_SEQ;

  short8 qf[8];
#pragma unroll
  for (int ds = 0; ds < 8; ++ds)
    qf[ds] = *reinterpret_cast<const short8*>(Qb + (size_t)l31 * DHD + ds * 16 + hi * 8);

  f32x16 accO[4];
#pragma unroll
  for (int dt = 0; dt < 4; ++dt)
#pragma unroll
    for (int r = 0; r < 16; ++r) accO[dt][r] = 0.f;
  float m = -1e30f, l = 0.f;

  int klo = q0 - (SWIN - 1); if (klo < 0) klo = 0;
  const int kt_lo = klo >> 5, kt_hi = q0 >> 5;
  const int qg = q0 + l31;

  for (int kt = kt_lo; kt <= kt_hi; ++kt) {
    const int k0 = kt << 5;
    short8 kf[8];
#pragma unroll
    for (int ds = 0; ds < 8; ++ds)
      kf[ds] = *reinterpret_cast<const short8*>(Kb + (size_t)(k0 + l31) * DHD + ds * 16 + hi * 8);

    f32x16 s;
#pragma unroll
    for (int r = 0; r < 16; ++r) s[r] = 0.f;
#pragma unroll
    for (int ds = 0; ds < 8; ++ds)
      s = __builtin_amdgcn_mfma_f32_32x32x16_bf16(kf[ds], qf[ds], s, 0, 0, 0);

    if (k0 < q0 - 480 || k0 >= q0) {
#pragma unroll
      for (int r = 0; r < 16; ++r) {
        int kk = k0 + (r & 3) + 8 * (r >> 2) + 4 * hi;
        if (kk > qg || qg - kk >= SWIN) s[r] = -1e30f;
      }
    }

    float tmax = s[0];
#pragma unroll
    for (int r = 1; r < 16; ++r) tmax = fmaxf(tmax, s[r]);
    tmax = fmaxf(tmax, __shfl_xor(tmax, 32));

    float mn = m;
    if (!__all(tmax <= m + 8.f)) {
      mn = fmaxf(m, tmax);
      float alpha = __expf(m - mn);
      l *= alpha;
#pragma unroll
      for (int dt = 0; dt < 4; ++dt)
#pragma unroll
        for (int r = 0; r < 16; ++r) accO[dt][r] *= alpha;
      m = mn;
    }

    float ps = 0.f;
#pragma unroll
    for (int r = 0; r < 16; ++r) { s[r] = __expf(s[r] - mn); ps += s[r]; }
    ps += __shfl_xor(ps, 32);
    l += ps;

    unsigned int w[8];
#pragma unroll
    for (int j = 0; j < 8; ++j)
      asm("v_cvt_pk_bf16_f32 %0, %1, %2" : "=v"(w[j]) : "v"(s[2 * j]), "v"(s[2 * j + 1]));
    asm("v_permlane32_swap_b32 %0, %1" : "+v"(w[0]), "+v"(w[2]));
    asm("v_permlane32_swap_b32 %0, %1" : "+v"(w[1]), "+v"(w[3]));
    asm("v_permlane32_swap_b32 %0, %1" : "+v"(w[4]), "+v"(w[6]));
    asm("v_permlane32_swap_b32 %0, %1" : "+v"(w[5]), "+v"(w[7]));
    u32x4 a0 = {w[0], w[1], w[2], w[3]};
    u32x4 a1 = {w[4], w[5], w[6], w[7]};
    short8 pf0 = __builtin_bit_cast(short8, a0);
    short8 pf1 = __builtin_bit_cast(short8, a1);

#pragma unroll
    for (int dt = 0; dt < 4; ++dt) {
      const unsigned short* vrow = Vb + (size_t)(dt * 32 + l31) * T_SEQ + k0 + hi * 8;
      short8 vf0 = *reinterpret_cast<const short8*>(vrow);
      short8 vf1 = *reinterpret_cast<const short8*>(vrow + 16);
      accO[dt] = __builtin_amdgcn_mfma_f32_32x32x16_bf16(vf0, pf0, accO[dt], 0, 0, 0);
      accO[dt] = __builtin_amdgcn_mfma_f32_32x32x16_bf16(vf1, pf1, accO[dt], 0, 0, 0);
    }
  }

  float inv = 1.f / l;
  unsigned short* obw = &ob[wid][0];
#pragma unroll
  for (int dt = 0; dt < 4; ++dt)
#pragma unroll
    for (int j = 0; j < 8; ++j) {
      float a = accO[dt][2 * j] * inv, c = accO[dt][2 * j + 1] * inv;
      unsigned int wv;
      asm("v_cvt_pk_bf16_f32 %0, %1, %2" : "=v"(wv) : "v"(a), "v"(c));
      int d = dt * 32 + 2 * (j & 1) + 8 * (j >> 1) + 4 * hi;
      *reinterpret_cast<unsigned int*>(obw + (size_t)l31 * 136 + d) = wv;
    }
  __syncthreads();
#pragma unroll
  for (int i = 0; i < 8; ++i) {
    int chunk = i * 64 + lane;
    int row = chunk >> 4, c8 = chunk & 15;
    short8 v = *reinterpret_cast<const short8*>(obw + row * 136 + c8 * 8);
    *reinterpret_cast<short8*>(Y + ((size_t)(b * T_SEQ) + q0 + row) * CDIM + h * DHD + c8 * 8) = v;
  }
}

extern "C" void kernel_launch(void* const* d_in, const int* in_sizes, int n_in,
                              void* d_out, int out_size, void* d_ws, size_t ws_size,
                              hipStream_t stream) {
  const float* x     = (const float*)d_in[0];
  const float* wqkv  = (const float*)d_in[1];
  const float* wproj = (const float*)d_in[2];
  float* out = (float*)d_out;

  char* ws = (char*)d_ws;
  unsigned short* xb     = (unsigned short*)(ws + 0);         // 16 MB (reused as y)
  unsigned short* wqkvb  = (unsigned short*)(ws + 16777216);  // 12 MB
  unsigned short* wprojb = (unsigned short*)(ws + 29360128);  // 8 MB
  unsigned short* qkvb   = (unsigned short*)(ws + 37748736);  // 24 MB
  unsigned short* Qb     = (unsigned short*)(ws + 62914560);  // 16 MB
  unsigned short* Kb     = (unsigned short*)(ws + 79691776);  // 4 MB
  unsigned short* Vtb    = (unsigned short*)(ws + 83886080);  // 4 MB
  float* tbl             = (float*)(ws + 88080384);           // 1 MB
  unsigned short* yb     = xb;

  k_f2bf<<<2048, 256, 0, stream>>>(x, xb, (NB * T_SEQ * CDIM) / 4);
  k_f2bf<<<1536, 256, 0, stream>>>(wqkv, wqkvb, (QKVN * CDIM) / 4);
  k_f2bf<<<1024, 256, 0, stream>>>(wproj, wprojb, (CDIM * CDIM) / 4);
  k_trig<<<(T_SEQ * 64 + 255) / 256, 256, 0, stream>>>(tbl);

  k_gemm256<1><<<(NB * T_SEQ / 256) * (QKVN / 256), 512, 131072, stream>>>(
      xb, wqkvb, qkvb, NB * T_SEQ, QKVN, CDIM, QKVN / 256);
  k_rope_rms<<<(NB * T_SEQ * (NHQ + NHKV)) / 4, 256, 0, stream>>>(qkvb, tbl, Qb, Kb);
  k_vtrans<<<NB * NHKV * 32 * 2, 256, 0, stream>>>(qkvb, Vtb);
  k_attn<<<NB * NHQ * (T_SEQ / 128), 256, 0, stream>>>(Qb, Kb, Vtb, yb);
  k_gemm256<0><<<(NB * T_SEQ / 256) * (CDIM / 256), 512, 131072, stream>>>(
      yb, wprojb, out, NB * T_SEQ, CDIM, CDIM, CDIM / 256);
}